// Round 19
// baseline (124.421 us; speedup 1.0000x reference)
//
#include <hip/hip_runtime.h>
#include <cstdint>

typedef __attribute__((ext_vector_type(8))) __bf16 bf16x8;
typedef __attribute__((ext_vector_type(4))) float f32x4;
typedef __attribute__((ext_vector_type(16))) float f32x16;
typedef __attribute__((ext_vector_type(4))) unsigned int u32x4;

#define DEV __device__ __forceinline__

DEV unsigned short f2bf(float f) {
    unsigned int u = __builtin_bit_cast(unsigned int, f);
    u += 0x7fffu + ((u >> 16) & 1u);   // RNE
    return (unsigned short)(u >> 16);
}

DEV void async_copy16(const void* g, void* l) {
    __builtin_amdgcn_global_load_lds(
        (const __attribute__((address_space(1))) unsigned int*)g,
        (__attribute__((address_space(3))) unsigned int*)l, 16, 0, 0);
}

DEV f32x4 mfma16(bf16x8 a, bf16x8 b, f32x4 c) {
    return __builtin_amdgcn_mfma_f32_16x16x32_bf16(a, b, c, 0, 0, 0);
}
DEV f32x16 mfma32(bf16x8 a, bf16x8 b, f32x16 c) {
    return __builtin_amdgcn_mfma_f32_32x32x16_bf16(a, b, c, 0, 0, 0);
}
DEV unsigned int cvtpk(float lo, float hi) {
    unsigned int d;
    asm("v_cvt_pk_bf16_f32 %0, %1, %2" : "=v"(d) : "v"(lo), "v"(hi));
    return d;
}
DEV float exp2f_fast(float x) { return __builtin_amdgcn_exp2f(x); }

// ---------------- f32 -> bf16 convert (vectorized) ----------------
__global__ __launch_bounds__(256) void convert_bf16(const float* __restrict__ in,
                                                    unsigned short* __restrict__ outp, int n) {
    int i = (blockIdx.x * 256 + threadIdx.x) * 4;
    if (i >= n) return;
    float4 v = *(const float4*)&in[i];
    ushort4 o;
    o.x = f2bf(v.x); o.y = f2bf(v.y); o.z = f2bf(v.z); o.w = f2bf(v.w);
    *(ushort4*)&outp[i] = o;
}

// ---------------- both weights: W[K][N] f32 -> Wt[N][K] bf16, one launch ----------------
__global__ __launch_bounds__(256) void transpose_convert2(const float* __restrict__ W1,
                                                          unsigned short* __restrict__ Wt1,
                                                          const float* __restrict__ W2,
                                                          unsigned short* __restrict__ Wt2) {
    __shared__ float tile[32][33];
    const int flat = (int)blockIdx.x;
    const float* W; unsigned short* Wt; int n0, k0, N;
    if (flat < 3072) { W = W1; Wt = Wt1; N = 3072; n0 = (flat % 96) * 32; k0 = (flat / 96) * 32; }
    else             { W = W2; Wt = Wt2; N = 1024; n0 = ((flat - 3072) % 32) * 32; k0 = ((flat - 3072) / 32) * 32; }
    const int K = 1024;
    int tx = threadIdx.x & 31, ty = threadIdx.x >> 5;  // ty 0..7
#pragma unroll
    for (int i = 0; i < 32; i += 8)
        tile[ty + i][tx] = W[(size_t)(k0 + ty + i) * N + n0 + tx];
    __syncthreads();
#pragma unroll
    for (int i = 0; i < 32; i += 8)
        Wt[(size_t)(n0 + ty + i) * K + k0 + tx] = f2bf(tile[tx][ty + i]);
}

// ---------------- GEMM v5: triple-buffered BK=32, counted vmcnt ----------------
template <int QKVMODE>
__global__ __launch_bounds__(256) void gemm_bt(const unsigned short* __restrict__ A,
                                               const unsigned short* __restrict__ Bt,
                                               const float* __restrict__ bias,
                                               void* __restrict__ Cout,
                                               unsigned short* __restrict__ KbOut,
                                               unsigned short* __restrict__ VtOut,
                                               int M, int N, int K, float qscaleV) {
    __shared__ __align__(16) unsigned short Asl[3][128][32];
    __shared__ __align__(16) unsigned short Bsl[3][128][32];
    const int tid = threadIdx.x;
    const int lane = tid & 63, w = tid >> 6;
    const int cl = lane & 15, kg = lane >> 4;

    const int nwg = (int)(gridDim.x * gridDim.y);
    const int flat = (int)(blockIdx.y * gridDim.x + blockIdx.x);
    const int swzb = (flat & 7) * (nwg >> 3) + (flat >> 3);
    const int m0 = (swzb % (int)gridDim.x) * 128;
    const int n0 = (swzb / (int)gridDim.x) * 128;

    const int wm = (w >> 1) * 64, wn = (w & 1) * 64;

    f32x4 acc[4][4] = {};

    const int srow16 = lane >> 2;
    const int sc4 = (lane & 3) ^ ((lane >> 3) & 3);
    const int rdswz = (cl >> 1) & 3;

    const int T = K >> 5;
#define GSTAGE(buf, t)                                                                    \
    {                                                                                     \
        const int k0_ = (t) << 5;                                                         \
        _Pragma("unroll")                                                                 \
        for (int j = 0; j < 2; ++j) {                                                     \
            const int row = w * 32 + j * 16;                                              \
            async_copy16(A + (size_t)(m0 + row + srow16) * K + k0_ + sc4 * 8,             \
                         &Asl[buf][row][0]);                                              \
            async_copy16(Bt + (size_t)(n0 + row + srow16) * K + k0_ + sc4 * 8,            \
                         &Bsl[buf][row][0]);                                              \
        }                                                                                 \
    }

    GSTAGE(0, 0);
    if (T > 1) GSTAGE(1, 1);

    for (int t = 0; t < T; ++t) {
        if (t + 1 < T)
            asm volatile("s_waitcnt vmcnt(4) lgkmcnt(0)" ::: "memory");
        else
            asm volatile("s_waitcnt vmcnt(0) lgkmcnt(0)" ::: "memory");
        __syncthreads();
        if (t + 2 < T) GSTAGE((t + 2) % 3, t + 2);

        const int cur = t % 3;
        bf16x8 af[4], bfv[4];
#pragma unroll
        for (int mf = 0; mf < 4; ++mf)
            af[mf] = *(const bf16x8*)&Asl[cur][wm + mf * 16 + cl][(kg ^ rdswz) * 8];
#pragma unroll
        for (int nf = 0; nf < 4; ++nf)
            bfv[nf] = *(const bf16x8*)&Bsl[cur][wn + nf * 16 + cl][(kg ^ rdswz) * 8];
        __builtin_amdgcn_s_setprio(1);
#pragma unroll
        for (int mf = 0; mf < 4; ++mf)
#pragma unroll
            for (int nf = 0; nf < 4; ++nf)
                acc[mf][nf] = mfma16(af[mf], bfv[nf], acc[mf][nf]);
        __builtin_amdgcn_s_setprio(0);
    }
#undef GSTAGE

#pragma unroll
    for (int mf = 0; mf < 4; ++mf) {
#pragma unroll
        for (int nf = 0; nf < 4; ++nf) {
            const int col = n0 + wn + nf * 16 + cl;
            const float bv = bias[col];
            const int row0 = m0 + wm + mf * 16 + kg * 4;
            if (QKVMODE == 0) {
#pragma unroll
                for (int r = 0; r < 4; ++r)
                    ((float*)Cout)[(size_t)(row0 + r) * N + col] = acc[mf][nf][r] + bv;
            } else if (col < 1024) {            // Q plane (pre-scaled for exp2 softmax)
#pragma unroll
                for (int r = 0; r < 4; ++r)
                    ((unsigned short*)Cout)[(size_t)(row0 + r) * 1024 + col] =
                        f2bf((acc[mf][nf][r] + bv) * qscaleV);
            } else if (col < 2048) {            // K plane
#pragma unroll
                for (int r = 0; r < 4; ++r)
                    KbOut[(size_t)(row0 + r) * 1024 + (col - 1024)] = f2bf(acc[mf][nf][r] + bv);
            } else {                            // V -> transposed Vt plane
                const int pcol = col - 2048;    // h*64 + d
                const int hh = pcol >> 6, dd = pcol & 63;
                const int bb = row0 >> 11, ss = row0 & 2047;
                ushort4 o;
                o.x = f2bf(acc[mf][nf][0] + bv);
                o.y = f2bf(acc[mf][nf][1] + bv);
                o.z = f2bf(acc[mf][nf][2] + bv);
                o.w = f2bf(acc[mf][nf][3] + bv);
                *(ushort4*)&VtOut[((size_t)(bb * 16 + hh) * 64 + dd) * 2048 + ss] = o;
            }
        }
    }
}

// ---------------- flash attention v18: long-strip 2-block split, PER-HEAD lsum ----------
// R17 bug: lsumG was indexed (b,row) -> 16 heads' row-sums collided (absmax 6.5e-2 =
// long rows' full magnitude). Fix: lsumG[(b*16+h)*1024 + row-1024] (128 KB), epilogue
// derives h = col>>6. Oacc accumulation was already per-head-safe (disjoint columns).
// Structure otherwise identical to R17: short strips (0..7) one block; long strips
// (8..15) two half-KV blocks merged via global f32 atomicAdd; longest serial depth 8.
__global__ __launch_bounds__(512) void attn_fwd18(const unsigned short* __restrict__ Qb,
                                                  const unsigned short* __restrict__ Kb,
                                                  const unsigned short* __restrict__ vt,
                                                  unsigned short* __restrict__ aout,
                                                  float* __restrict__ Oacc,
                                                  float* __restrict__ lsumG) {
    constexpr int S = 2048;
    constexpr float MOFF = 8.0f;                // fixed softmax offset (exp2 domain)
    __shared__ __align__(16) unsigned short SM[2][2][2][64 * 64];
    const int tid = threadIdx.x;
    const int l = tid & 63, w = tid >> 6;       // 8 waves
    const int q31 = l & 31, hi = l >> 5;
    const int rg = w & 3, kvh = w >> 2;         // row-group 0..3, kv-half 0..1

    // XCD-local mapping: id 0..767 -> (bh, slot k)
    const int id = (int)blockIdx.x;
    const int x = id & 7, u = id >> 3;          // u 0..95
    const int bh = x * 4 + (u & 3);
    const int k = u >> 2;                       // 0..23
    int strip, halfsel, isLong;
    if (k < 8) { strip = k;              halfsel = 0;     isLong = 0; }
    else       { const int p = k - 8;    strip = 8 + (p >> 1); halfsel = p & 1; isLong = 1; }

    const int sp1 = strip + 1;
    int tb0, tb1, nt1, Th;
    if (!isLong) { tb0 = 0;             tb1 = sp1;        nt1 = sp1;       Th = sp1; }
    else { const int Th1 = (strip + 2) >> 1;
           tb0 = halfsel * sp1;         tb1 = tb0 + Th1;  nt1 = sp1 - Th1; Th = Th1; }

    const int b = bh >> 4, h = bh & 15;
    const int q0 = strip * 128 + rg * 32;
    const int q = q0 + q31;
    const unsigned short* Qp = Qb + (size_t)b * S * 1024 + h * 64;
    const unsigned short* Kp = Kb + (size_t)b * S * 1024 + h * 64;
    const unsigned short* Vtp = vt + (size_t)bh * 64 * S;

    bf16x8 qf[4];
#pragma unroll
    for (int kf = 0; kf < 4; ++kf)
        qf[kf] = *(const bf16x8*)&Qp[(size_t)q * 1024 + kf * 16 + hi * 8];

    float lsum = 0.f;
    f32x16 oacc[2] = {};

    const int srow = l >> 3;                    // 0..7 within the 8-row group
    const int sc16 = (l & 7) ^ srow;            // pre-swizzled source col16
    const int swz = q31 & 7;                    // read-side XOR for this lane's rows

    const int row8 = w * 8;                     // this wave's 8-row staging slab

#define STAGE(buf, t)                                                                   \
    {                                                                                   \
        const int sA = (tb0 + (t)) * 64;                                                \
        const int tB = tb1 + ((t) < nt1 ? (t) : nt1 - 1);                               \
        const int sB = tB * 64;                                                         \
        async_copy16(Kp + (size_t)(sA + row8 + srow) * 1024 + sc16 * 8,                 \
                     &SM[0][buf][0][row8 * 64]);                                        \
        async_copy16(Kp + (size_t)(sB + row8 + srow) * 1024 + sc16 * 8,                 \
                     &SM[0][buf][1][row8 * 64]);                                        \
        async_copy16(Vtp + (size_t)(row8 + srow) * S + sA + sc16 * 8,                   \
                     &SM[1][buf][0][row8 * 64]);                                        \
        async_copy16(Vtp + (size_t)(row8 + srow) * S + sB + sc16 * 8,                   \
                     &SM[1][buf][1][row8 * 64]);                                        \
    }

    STAGE(0, 0);
    int cur = 0;

    for (int t = 0; t < Th; ++t) {
        // explicit drain (R7): staging writes landed, prev-buffer reads complete
        asm volatile("s_waitcnt vmcnt(0) lgkmcnt(0)" ::: "memory");
        __syncthreads();
        if (t + 1 < Th) STAGE(cur ^ 1, t + 1);

        const bool validB = (t < nt1);
        const int tw = (kvh ? tb1 : tb0) + t;
        const int s0 = (kvh && !validB) ? (1 << 20) : tw * 64;

        // ---- K frags from swizzled LDS ----
        bf16x8 kb[2][4];
#pragma unroll
        for (int kt = 0; kt < 2; ++kt)
#pragma unroll
            for (int kf = 0; kf < 4; ++kf)
                kb[kt][kf] = *(const bf16x8*)&SM[0][cur][kvh][(kt * 32 + q31) * 64 + ((kf * 2 + hi) ^ swz) * 8];

        // ---- T[key][q] = K @ Q^T (swapped) ----
        f32x16 tacc[2] = {};
        __builtin_amdgcn_s_setprio(1);
#pragma unroll
        for (int kt = 0; kt < 2; ++kt)
#pragma unroll
            for (int kf = 0; kf < 4; ++kf)
                tacc[kt] = mfma32(kb[kt][kf], qf[kf], tacc[kt]);
        __builtin_amdgcn_s_setprio(0);

        // ---- V frags from swizzled LDS ----
        bf16x8 vb[2][4];
#pragma unroll
        for (int df = 0; df < 2; ++df)
#pragma unroll
            for (int ks = 0; ks < 4; ++ks)
                vb[df][ks] = *(const bf16x8*)&SM[1][cur][kvh][(df * 32 + q31) * 64 + ((ks * 2 + hi) ^ swz) * 8];

        // ---- causal mask (covers padded iterations: s0 huge -> all masked) ----
        const bool partial = (s0 + 63 > q0);
        float pv[2][16];
        if (partial) {
#pragma unroll
            for (int kt = 0; kt < 2; ++kt)
#pragma unroll
                for (int r = 0; r < 16; ++r) {
                    const int key = s0 + kt * 32 + (r & 3) + ((r >> 2) << 3) + hi * 4;
                    float sv = tacc[kt][r];
                    if (key > q) sv = -1e30f;
                    pv[kt][r] = sv;
                }
        } else {
#pragma unroll
            for (int kt = 0; kt < 2; ++kt)
#pragma unroll
                for (int r = 0; r < 16; ++r) pv[kt][r] = tacc[kt][r];
        }

        // ---- exp2 (fixed offset) + pack + row sum ----
        unsigned int pk[2][4][2];
        float rsum = 0.f;
#pragma unroll
        for (int kt = 0; kt < 2; ++kt)
#pragma unroll
            for (int g = 0; g < 4; ++g) {
                const float e0 = exp2f_fast(pv[kt][g * 4 + 0] - MOFF);
                const float e1 = exp2f_fast(pv[kt][g * 4 + 1] - MOFF);
                const float e2 = exp2f_fast(pv[kt][g * 4 + 2] - MOFF);
                const float e3 = exp2f_fast(pv[kt][g * 4 + 3] - MOFF);
                pk[kt][g][0] = cvtpk(e0, e1);
                pk[kt][g][1] = cvtpk(e2, e3);
                rsum += (e0 + e1) + (e2 + e3);
            }
        rsum += __shfl_xor(rsum, 32, 64);
        lsum += rsum;

        // ---- PV: select-based PA assembly (shfl half-swap, verified) ----
#pragma unroll
        for (int ks = 0; ks < 4; ++ks) {
            const int kt = ks >> 1, kslo = ks & 1;
            const unsigned int pkA0 = pk[kt][2 * kslo][0],     pkA1 = pk[kt][2 * kslo][1];
            const unsigned int pkB0 = pk[kt][2 * kslo + 1][0], pkB1 = pk[kt][2 * kslo + 1][1];
            const unsigned int send0 = hi ? pkA0 : pkB0;
            const unsigned int send1 = hi ? pkA1 : pkB1;
            const unsigned int own0  = hi ? pkB0 : pkA0;
            const unsigned int own1  = hi ? pkB1 : pkA1;
            const unsigned int recv0 = (unsigned int)__shfl_xor((int)send0, 32, 64);
            const unsigned int recv1 = (unsigned int)__shfl_xor((int)send1, 32, 64);
            u32x4 u4;
            u4[0] = hi ? recv0 : own0;
            u4[1] = hi ? recv1 : own1;
            u4[2] = hi ? own0 : recv0;
            u4[3] = hi ? own1 : recv1;
            const bf16x8 pa = __builtin_bit_cast(bf16x8, u4);
            __builtin_amdgcn_s_setprio(1);
            oacc[0] = mfma32(pa, vb[0][ks], oacc[0]);
            oacc[1] = mfma32(pa, vb[1][ks], oacc[1]);
            __builtin_amdgcn_s_setprio(0);
        }
        cur ^= 1;
    }
#undef STAGE

    // ---- in-block kvh merge (LINEAR) ----
    asm volatile("s_waitcnt vmcnt(0) lgkmcnt(0)" ::: "memory");
    __syncthreads();                            // loop LDS reads done; safe to reuse
    float* fl = (float*)&SM[0][0][0][0];        // [4][64][36] f32 = 36 KB
    float* p = fl + ((size_t)rg * 64 + l) * 36;
    if (kvh == 1) {
#pragma unroll
        for (int d = 0; d < 2; ++d)
#pragma unroll
            for (int g = 0; g < 4; ++g)
                *(f32x4*)(p + d * 16 + g * 4) = f32x4{oacc[d][g * 4 + 0], oacc[d][g * 4 + 1],
                                                      oacc[d][g * 4 + 2], oacc[d][g * 4 + 3]};
        p[32] = lsum;
    }
    asm volatile("s_waitcnt lgkmcnt(0)" ::: "memory");
    __syncthreads();
    if (kvh == 1) return;

#pragma unroll
    for (int d = 0; d < 2; ++d)
#pragma unroll
        for (int g = 0; g < 4; ++g) {
            const f32x4 v = *(const f32x4*)(p + d * 16 + g * 4);
#pragma unroll
            for (int e = 0; e < 4; ++e) oacc[d][g * 4 + e] += v[e];
        }
    lsum += p[32];

    if (!isLong) {
        // ---- short strip: direct epilogue ----
        const float linv = 1.f / lsum;
#pragma unroll
        for (int r = 0; r < 16; ++r) {
            const int qrow = (r & 3) + ((r >> 2) << 3) + hi * 4;
            const float lr = __shfl(linv, qrow, 64);
            const int row = q0 + qrow;
            aout[(size_t)(b * S + row) * 1024 + h * 64 + q31]      = f2bf(oacc[0][r] * lr);
            aout[(size_t)(b * S + row) * 1024 + h * 64 + 32 + q31] = f2bf(oacc[1][r] * lr);
        }
    } else {
        // ---- long strip: accumulate partials globally (rows >= 1024), PER-HEAD lsum ----
        if (hi == 0) {
            const int lhrow = ((b * 16 + h) << 10) + (q0 + q31 - 1024);
            atomicAdd(&lsumG[lhrow], lsum);
        }
#pragma unroll
        for (int r = 0; r < 16; ++r) {
            const int qrow = (r & 3) + ((r >> 2) << 3) + hi * 4;
            const int lrow = b * 1024 + (q0 + qrow - 1024);
            atomicAdd(&Oacc[(size_t)lrow * 1024 + h * 64 + q31],      oacc[0][r]);
            atomicAdd(&Oacc[(size_t)lrow * 1024 + h * 64 + 32 + q31], oacc[1][r]);
        }
    }
}

// ---------------- attn epilogue: rows >= 1024 -> AO bf16 (per-head lsum) ----------------
__global__ __launch_bounds__(256) void attn_epilogue(const float* __restrict__ Oacc,
                                                     const float* __restrict__ lsumG,
                                                     unsigned short* __restrict__ aout) {
    const int lrow = (int)blockIdx.x;           // 0..2047 = b*1024 + (row-1024)
    const int b = lrow >> 10, row = 1024 + (lrow & 1023);
    const int col = (int)threadIdx.x * 4;       // 4 cols, same head (64-aligned bands)
    const int h = col >> 6;
    const float linv = 1.f / lsumG[((b * 16 + h) << 10) + (lrow & 1023)];
    const f32x4 v = *(const f32x4*)&Oacc[(size_t)lrow * 1024 + col];
    ushort4 o;
    o.x = f2bf(v[0] * linv); o.y = f2bf(v[1] * linv);
    o.z = f2bf(v[2] * linv); o.w = f2bf(v[3] * linv);
    *(ushort4*)&aout[(size_t)(b * 2048 + row) * 1024 + col] = o;
}

extern "C" void kernel_launch(void* const* d_in, const int* in_sizes, int n_in,
                              void* d_out, int out_size, void* d_ws, size_t ws_size,
                              hipStream_t stream) {
    (void)in_sizes; (void)n_in; (void)out_size; (void)ws_size;
    const float* hs    = (const float*)d_in[0];  // [2,2048,1024]
    const float* wqkv  = (const float*)d_in[1];  // [1024,3072]
    const float* bqkv  = (const float*)d_in[2];  // [3072]
    const float* wproj = (const float*)d_in[3];  // [1024,1024]
    const float* bproj = (const float*)d_in[4];  // [1024]
    float* out = (float*)d_out;                  // [2,2048,1024] f32

    unsigned short* Xb  = (unsigned short*)d_ws;                 // 4096*1024 (dead after QKV GEMM)
    unsigned short* Wqt = Xb  + (size_t)4096 * 1024;             // 3072*1024 (dead after QKV GEMM)
    unsigned short* Wpt = Wqt + (size_t)3072 * 1024;             // 1024*1024
    unsigned short* Qb  = Wpt + (size_t)1024 * 1024;             // 4096*1024
    unsigned short* Kb  = Qb  + (size_t)4096 * 1024;             // 4096*1024
    unsigned short* Vt  = Kb  + (size_t)4096 * 1024;             // 32*64*2048
    unsigned short* AO  = Vt  + (size_t)4096 * 1024;             // 4096*1024

    // attn partial buffers reuse dead regions: Oacc (2048x1024 f32 = 8.39 MB) in Xb;
    // lsumG (2*16*1024 f32 = 128 KB, PER-HEAD) at start of Wqt (contiguous with Xb).
    float* Oacc  = (float*)Xb;
    float* lsumG = (float*)Wqt;

    const float qscale = 0.125f * 1.4426950408889634f;  // softmax scale + log2e into Q

    convert_bf16<<<4096, 256, 0, stream>>>(hs, Xb, 4096 * 1024);
    transpose_convert2<<<4096, 256, 0, stream>>>(wqkv, Wqt, wproj, Wpt);

    gemm_bt<1><<<dim3(32, 24), 256, 0, stream>>>(Xb, Wqt, bqkv, (void*)Qb, Kb, Vt,
                                                 4096, 3072, 1024, qscale);
    // zero the accumulators (stream-ordered: after QKV GEMM frees Xb/Wqt)
    hipMemsetAsync((void*)Oacc, 0, (size_t)2048 * 1024 * 4 + (size_t)32768 * 4, stream);
    attn_fwd18<<<768, 512, 0, stream>>>(Qb, Kb, Vt, AO, Oacc, lsumG);
    attn_epilogue<<<2048, 256, 0, stream>>>(Oacc, lsumG, AO);
    gemm_bt<0><<<dim3(32, 8), 256, 0, stream>>>(AO, Wpt, bproj, (void*)out, nullptr, nullptr,
                                                4096, 1024, 1024, 1.0f);
}

// Round 20
// 113.398 us; speedup vs baseline: 1.0972x; 1.0972x over previous
//
#include <hip/hip_runtime.h>
#include <cstdint>

typedef __attribute__((ext_vector_type(8))) __bf16 bf16x8;
typedef __attribute__((ext_vector_type(4))) float f32x4;
typedef __attribute__((ext_vector_type(16))) float f32x16;
typedef __attribute__((ext_vector_type(4))) unsigned int u32x4;

#define DEV __device__ __forceinline__

DEV unsigned short f2bf(float f) {
    unsigned int u = __builtin_bit_cast(unsigned int, f);
    u += 0x7fffu + ((u >> 16) & 1u);   // RNE
    return (unsigned short)(u >> 16);
}

DEV void async_copy16(const void* g, void* l) {
    __builtin_amdgcn_global_load_lds(
        (const __attribute__((address_space(1))) unsigned int*)g,
        (__attribute__((address_space(3))) unsigned int*)l, 16, 0, 0);
}

DEV f32x4 mfma16(bf16x8 a, bf16x8 b, f32x4 c) {
    return __builtin_amdgcn_mfma_f32_16x16x32_bf16(a, b, c, 0, 0, 0);
}
DEV f32x16 mfma32(bf16x8 a, bf16x8 b, f32x16 c) {
    return __builtin_amdgcn_mfma_f32_32x32x16_bf16(a, b, c, 0, 0, 0);
}
DEV unsigned int cvtpk(float lo, float hi) {
    unsigned int d;
    asm("v_cvt_pk_bf16_f32 %0, %1, %2" : "=v"(d) : "v"(lo), "v"(hi));
    return d;
}
DEV float exp2f_fast(float x) { return __builtin_amdgcn_exp2f(x); }

// ---------------- f32 -> bf16 convert (vectorized) ----------------
__global__ __launch_bounds__(256) void convert_bf16(const float* __restrict__ in,
                                                    unsigned short* __restrict__ outp, int n) {
    int i = (blockIdx.x * 256 + threadIdx.x) * 4;
    if (i >= n) return;
    float4 v = *(const float4*)&in[i];
    ushort4 o;
    o.x = f2bf(v.x); o.y = f2bf(v.y); o.z = f2bf(v.z); o.w = f2bf(v.w);
    *(ushort4*)&outp[i] = o;
}

// ---------------- both weights: W[K][N] f32 -> Wt[N][K] bf16, one launch ----------------
__global__ __launch_bounds__(256) void transpose_convert2(const float* __restrict__ W1,
                                                          unsigned short* __restrict__ Wt1,
                                                          const float* __restrict__ W2,
                                                          unsigned short* __restrict__ Wt2) {
    __shared__ float tile[32][33];
    const int flat = (int)blockIdx.x;
    const float* W; unsigned short* Wt; int n0, k0, N;
    if (flat < 3072) { W = W1; Wt = Wt1; N = 3072; n0 = (flat % 96) * 32; k0 = (flat / 96) * 32; }
    else             { W = W2; Wt = Wt2; N = 1024; n0 = ((flat - 3072) % 32) * 32; k0 = ((flat - 3072) / 32) * 32; }
    const int K = 1024;
    int tx = threadIdx.x & 31, ty = threadIdx.x >> 5;  // ty 0..7
#pragma unroll
    for (int i = 0; i < 32; i += 8)
        tile[ty + i][tx] = W[(size_t)(k0 + ty + i) * N + n0 + tx];
    __syncthreads();
#pragma unroll
    for (int i = 0; i < 32; i += 8)
        Wt[(size_t)(n0 + ty + i) * K + k0 + tx] = f2bf(tile[tx][ty + i]);
}

// ---------------- GEMM v5: triple-buffered BK=32, counted vmcnt ----------------
template <int QKVMODE>
__global__ __launch_bounds__(256) void gemm_bt(const unsigned short* __restrict__ A,
                                               const unsigned short* __restrict__ Bt,
                                               const float* __restrict__ bias,
                                               void* __restrict__ Cout,
                                               unsigned short* __restrict__ KbOut,
                                               unsigned short* __restrict__ VtOut,
                                               int M, int N, int K, float qscaleV) {
    __shared__ __align__(16) unsigned short Asl[3][128][32];
    __shared__ __align__(16) unsigned short Bsl[3][128][32];
    const int tid = threadIdx.x;
    const int lane = tid & 63, w = tid >> 6;
    const int cl = lane & 15, kg = lane >> 4;

    const int nwg = (int)(gridDim.x * gridDim.y);
    const int flat = (int)(blockIdx.y * gridDim.x + blockIdx.x);
    const int swzb = (flat & 7) * (nwg >> 3) + (flat >> 3);
    const int m0 = (swzb % (int)gridDim.x) * 128;
    const int n0 = (swzb / (int)gridDim.x) * 128;

    const int wm = (w >> 1) * 64, wn = (w & 1) * 64;

    f32x4 acc[4][4] = {};

    const int srow16 = lane >> 2;
    const int sc4 = (lane & 3) ^ ((lane >> 3) & 3);
    const int rdswz = (cl >> 1) & 3;

    const int T = K >> 5;
#define GSTAGE(buf, t)                                                                    \
    {                                                                                     \
        const int k0_ = (t) << 5;                                                         \
        _Pragma("unroll")                                                                 \
        for (int j = 0; j < 2; ++j) {                                                     \
            const int row = w * 32 + j * 16;                                              \
            async_copy16(A + (size_t)(m0 + row + srow16) * K + k0_ + sc4 * 8,             \
                         &Asl[buf][row][0]);                                              \
            async_copy16(Bt + (size_t)(n0 + row + srow16) * K + k0_ + sc4 * 8,            \
                         &Bsl[buf][row][0]);                                              \
        }                                                                                 \
    }

    GSTAGE(0, 0);
    if (T > 1) GSTAGE(1, 1);

    for (int t = 0; t < T; ++t) {
        if (t + 1 < T)
            asm volatile("s_waitcnt vmcnt(4) lgkmcnt(0)" ::: "memory");
        else
            asm volatile("s_waitcnt vmcnt(0) lgkmcnt(0)" ::: "memory");
        __syncthreads();
        if (t + 2 < T) GSTAGE((t + 2) % 3, t + 2);

        const int cur = t % 3;
        bf16x8 af[4], bfv[4];
#pragma unroll
        for (int mf = 0; mf < 4; ++mf)
            af[mf] = *(const bf16x8*)&Asl[cur][wm + mf * 16 + cl][(kg ^ rdswz) * 8];
#pragma unroll
        for (int nf = 0; nf < 4; ++nf)
            bfv[nf] = *(const bf16x8*)&Bsl[cur][wn + nf * 16 + cl][(kg ^ rdswz) * 8];
        __builtin_amdgcn_s_setprio(1);
#pragma unroll
        for (int mf = 0; mf < 4; ++mf)
#pragma unroll
            for (int nf = 0; nf < 4; ++nf)
                acc[mf][nf] = mfma16(af[mf], bfv[nf], acc[mf][nf]);
        __builtin_amdgcn_s_setprio(0);
    }
#undef GSTAGE

#pragma unroll
    for (int mf = 0; mf < 4; ++mf) {
#pragma unroll
        for (int nf = 0; nf < 4; ++nf) {
            const int col = n0 + wn + nf * 16 + cl;
            const float bv = bias[col];
            const int row0 = m0 + wm + mf * 16 + kg * 4;
            if (QKVMODE == 0) {
#pragma unroll
                for (int r = 0; r < 4; ++r)
                    ((float*)Cout)[(size_t)(row0 + r) * N + col] = acc[mf][nf][r] + bv;
            } else if (col < 1024) {            // Q plane (pre-scaled for exp2 softmax)
#pragma unroll
                for (int r = 0; r < 4; ++r)
                    ((unsigned short*)Cout)[(size_t)(row0 + r) * 1024 + col] =
                        f2bf((acc[mf][nf][r] + bv) * qscaleV);
            } else if (col < 2048) {            // K plane
#pragma unroll
                for (int r = 0; r < 4; ++r)
                    KbOut[(size_t)(row0 + r) * 1024 + (col - 1024)] = f2bf(acc[mf][nf][r] + bv);
            } else {                            // V -> transposed Vt plane
                const int pcol = col - 2048;    // h*64 + d
                const int hh = pcol >> 6, dd = pcol & 63;
                const int bb = row0 >> 11, ss = row0 & 2047;
                ushort4 o;
                o.x = f2bf(acc[mf][nf][0] + bv);
                o.y = f2bf(acc[mf][nf][1] + bv);
                o.z = f2bf(acc[mf][nf][2] + bv);
                o.w = f2bf(acc[mf][nf][3] + bv);
                *(ushort4*)&VtOut[((size_t)(bb * 16 + hh) * 64 + dd) * 2048 + ss] = o;
            }
        }
    }
}

// ---------------- flash attention v16: intra-block split-KV (8 waves) ----------------
// Measured-best attn (R16/R17-input: 42.4 us, total 112.7). 8 waves = 4 row-groups x
// 2 KV-halves; fixed-offset softmax makes partials linear -> LDS merge, no atomics.
// R18 lesson: cross-block split w/ global atomic merge cost more than the 8-iteration
// tail it saved (atomic traffic + memset + epilogue + 3rd dispatch round).
__global__ __launch_bounds__(512) void attn_fwd16(const unsigned short* __restrict__ Qb,
                                                  const unsigned short* __restrict__ Kb,
                                                  const unsigned short* __restrict__ vt,
                                                  unsigned short* __restrict__ aout) {
    constexpr int S = 2048;
    constexpr float MOFF = 8.0f;                // fixed softmax offset (exp2 domain)
    __shared__ __align__(16) unsigned short SM[2][2][2][64 * 64];
    const int tid = threadIdx.x;
    const int l = tid & 63, w = tid >> 6;       // 8 waves
    const int q31 = l & 31, hi = l >> 5;
    const int rg = w & 3, kvh = w >> 2;         // row-group 0..3, kv-half 0..1

    // XCD-local mapping (R12) + complementary pairing
    const int id = (int)(blockIdx.y * gridDim.x + blockIdx.x);
    const int hblk = id >> 8, c = id & 255;
    const int x = c & 7, u = c >> 3;            // x = XCD, u = 0..31
    const int bh = x * 4 + (u & 3);
    const int j = u >> 2;                       // 0..7
    const int strip = hblk ? j : 15 - j;

    const int b = bh >> 4, h = bh & 15;
    const int q0 = strip * 128 + rg * 32;
    const int q = q0 + q31;
    const unsigned short* Qp = Qb + (size_t)b * S * 1024 + h * 64;
    const unsigned short* Kp = Kb + (size_t)b * S * 1024 + h * 64;
    const unsigned short* Vtp = vt + (size_t)bh * 64 * S;

    bf16x8 qf[4];
#pragma unroll
    for (int kf = 0; kf < 4; ++kf)
        qf[kf] = *(const bf16x8*)&Qp[(size_t)q * 1024 + kf * 16 + hi * 8];

    float lsum = 0.f;
    f32x16 oacc[2] = {};

    const int srow = l >> 3;                    // 0..7 within the 8-row group
    const int sc16 = (l & 7) ^ srow;            // pre-swizzled source col16
    const int swz = q31 & 7;                    // read-side XOR for this lane's rows

    const int Th = strip + 1;                   // tiles per KV-half
    const int row8 = w * 8;                     // this wave's 8-row slab

#define STAGE(buf, t)                                                                   \
    {                                                                                   \
        const int sA = (t) * 64;                                                        \
        const int sB = (Th + (t)) * 64;                                                 \
        async_copy16(Kp + (size_t)(sA + row8 + srow) * 1024 + sc16 * 8,                 \
                     &SM[0][buf][0][row8 * 64]);                                        \
        async_copy16(Kp + (size_t)(sB + row8 + srow) * 1024 + sc16 * 8,                 \
                     &SM[0][buf][1][row8 * 64]);                                        \
        async_copy16(Vtp + (size_t)(row8 + srow) * S + sA + sc16 * 8,                   \
                     &SM[1][buf][0][row8 * 64]);                                        \
        async_copy16(Vtp + (size_t)(row8 + srow) * S + sB + sc16 * 8,                   \
                     &SM[1][buf][1][row8 * 64]);                                        \
    }

    STAGE(0, 0);
    int cur = 0;

    for (int t = 0; t < Th; ++t) {
        // explicit drain (R7): staging writes landed, prev-buffer reads complete
        asm volatile("s_waitcnt vmcnt(0) lgkmcnt(0)" ::: "memory");
        __syncthreads();
        if (t + 1 < Th) STAGE(cur ^ 1, t + 1);

        const int s0 = (kvh * Th + t) * 64;

        // ---- K frags from swizzled LDS ----
        bf16x8 kb[2][4];
#pragma unroll
        for (int kt = 0; kt < 2; ++kt)
#pragma unroll
            for (int kf = 0; kf < 4; ++kf)
                kb[kt][kf] = *(const bf16x8*)&SM[0][cur][kvh][(kt * 32 + q31) * 64 + ((kf * 2 + hi) ^ swz) * 8];

        // ---- T[key][q] = K @ Q^T (swapped) ----
        f32x16 tacc[2] = {};
        __builtin_amdgcn_s_setprio(1);
#pragma unroll
        for (int kt = 0; kt < 2; ++kt)
#pragma unroll
            for (int kf = 0; kf < 4; ++kf)
                tacc[kt] = mfma32(kb[kt][kf], qf[kf], tacc[kt]);
        __builtin_amdgcn_s_setprio(0);

        // ---- V frags from swizzled LDS ----
        bf16x8 vb[2][4];
#pragma unroll
        for (int df = 0; df < 2; ++df)
#pragma unroll
            for (int ks = 0; ks < 4; ++ks)
                vb[df][ks] = *(const bf16x8*)&SM[1][cur][kvh][(df * 32 + q31) * 64 + ((ks * 2 + hi) ^ swz) * 8];

        // ---- causal mask: only partial tiles pay ----
        const bool partial = (s0 + 63 > q0);
        float pv[2][16];
        if (partial) {
#pragma unroll
            for (int kt = 0; kt < 2; ++kt)
#pragma unroll
                for (int r = 0; r < 16; ++r) {
                    const int key = s0 + kt * 32 + (r & 3) + ((r >> 2) << 3) + hi * 4;
                    float sv = tacc[kt][r];
                    if (key > q) sv = -1e30f;
                    pv[kt][r] = sv;
                }
        } else {
#pragma unroll
            for (int kt = 0; kt < 2; ++kt)
#pragma unroll
                for (int r = 0; r < 16; ++r) pv[kt][r] = tacc[kt][r];
        }

        // ---- exp2 (fixed offset) + pack + row sum ----
        unsigned int pk[2][4][2];
        float rsum = 0.f;
#pragma unroll
        for (int kt = 0; kt < 2; ++kt)
#pragma unroll
            for (int g = 0; g < 4; ++g) {
                const float e0 = exp2f_fast(pv[kt][g * 4 + 0] - MOFF);
                const float e1 = exp2f_fast(pv[kt][g * 4 + 1] - MOFF);
                const float e2 = exp2f_fast(pv[kt][g * 4 + 2] - MOFF);
                const float e3 = exp2f_fast(pv[kt][g * 4 + 3] - MOFF);
                pk[kt][g][0] = cvtpk(e0, e1);
                pk[kt][g][1] = cvtpk(e2, e3);
                rsum += (e0 + e1) + (e2 + e3);
            }
        rsum += __shfl_xor(rsum, 32, 64);
        lsum += rsum;

        // ---- PV: select-based PA assembly (shfl half-swap, verified) ----
#pragma unroll
        for (int ks = 0; ks < 4; ++ks) {
            const int kt = ks >> 1, kslo = ks & 1;
            const unsigned int pkA0 = pk[kt][2 * kslo][0],     pkA1 = pk[kt][2 * kslo][1];
            const unsigned int pkB0 = pk[kt][2 * kslo + 1][0], pkB1 = pk[kt][2 * kslo + 1][1];
            const unsigned int send0 = hi ? pkA0 : pkB0;
            const unsigned int send1 = hi ? pkA1 : pkB1;
            const unsigned int own0  = hi ? pkB0 : pkA0;
            const unsigned int own1  = hi ? pkB1 : pkA1;
            const unsigned int recv0 = (unsigned int)__shfl_xor((int)send0, 32, 64);
            const unsigned int recv1 = (unsigned int)__shfl_xor((int)send1, 32, 64);
            u32x4 u4;
            u4[0] = hi ? recv0 : own0;
            u4[1] = hi ? recv1 : own1;
            u4[2] = hi ? own0 : recv0;
            u4[3] = hi ? own1 : recv1;
            const bf16x8 pa = __builtin_bit_cast(bf16x8, u4);
            __builtin_amdgcn_s_setprio(1);
            oacc[0] = mfma32(pa, vb[0][ks], oacc[0]);
            oacc[1] = mfma32(pa, vb[1][ks], oacc[1]);
            __builtin_amdgcn_s_setprio(0);
        }
        cur ^= 1;
    }
#undef STAGE

    // ---- merge halves (LINEAR: fixed-offset softmax has no running max) ----
    asm volatile("s_waitcnt vmcnt(0) lgkmcnt(0)" ::: "memory");
    __syncthreads();                            // loop LDS reads done; safe to reuse
    float* fl = (float*)&SM[0][0][0][0];        // [4][64][36] f32 = 36 KB
    float* p = fl + ((size_t)rg * 64 + l) * 36; // 144 B stride (16B-aligned)
    if (kvh == 1) {
#pragma unroll
        for (int d = 0; d < 2; ++d)
#pragma unroll
            for (int g = 0; g < 4; ++g)
                *(f32x4*)(p + d * 16 + g * 4) = f32x4{oacc[d][g * 4 + 0], oacc[d][g * 4 + 1],
                                                      oacc[d][g * 4 + 2], oacc[d][g * 4 + 3]};
        p[32] = lsum;
    }
    asm volatile("s_waitcnt lgkmcnt(0)" ::: "memory");
    __syncthreads();
    if (kvh == 1) return;

#pragma unroll
    for (int d = 0; d < 2; ++d)
#pragma unroll
        for (int g = 0; g < 4; ++g) {
            const f32x4 v = *(const f32x4*)(p + d * 16 + g * 4);
#pragma unroll
            for (int e = 0; e < 4; ++e) oacc[d][g * 4 + e] += v[e];
        }
    lsum += p[32];

    // ---- epilogue: O /= l ----
    const float linv = 1.f / lsum;
#pragma unroll
    for (int r = 0; r < 16; ++r) {
        const int qrow = (r & 3) + ((r >> 2) << 3) + hi * 4;
        const float lr = __shfl(linv, qrow, 64);
        const int row = q0 + qrow;
        aout[(size_t)(b * S + row) * 1024 + h * 64 + q31]      = f2bf(oacc[0][r] * lr);
        aout[(size_t)(b * S + row) * 1024 + h * 64 + 32 + q31] = f2bf(oacc[1][r] * lr);
    }
}

extern "C" void kernel_launch(void* const* d_in, const int* in_sizes, int n_in,
                              void* d_out, int out_size, void* d_ws, size_t ws_size,
                              hipStream_t stream) {
    (void)in_sizes; (void)n_in; (void)out_size; (void)ws_size;
    const float* hs    = (const float*)d_in[0];  // [2,2048,1024]
    const float* wqkv  = (const float*)d_in[1];  // [1024,3072]
    const float* bqkv  = (const float*)d_in[2];  // [3072]
    const float* wproj = (const float*)d_in[3];  // [1024,1024]
    const float* bproj = (const float*)d_in[4];  // [1024]
    float* out = (float*)d_out;                  // [2,2048,1024] f32

    unsigned short* Xb  = (unsigned short*)d_ws;                 // 4096*1024
    unsigned short* Wqt = Xb  + (size_t)4096 * 1024;             // 3072*1024
    unsigned short* Wpt = Wqt + (size_t)3072 * 1024;             // 1024*1024
    unsigned short* Qb  = Wpt + (size_t)1024 * 1024;             // 4096*1024
    unsigned short* Kb  = Qb  + (size_t)4096 * 1024;             // 4096*1024
    unsigned short* Vt  = Kb  + (size_t)4096 * 1024;             // 32*64*2048
    unsigned short* AO  = Vt  + (size_t)4096 * 1024;             // 4096*1024

    const float qscale = 0.125f * 1.4426950408889634f;  // softmax scale + log2e into Q

    convert_bf16<<<4096, 256, 0, stream>>>(hs, Xb, 4096 * 1024);
    transpose_convert2<<<4096, 256, 0, stream>>>(wqkv, Wqt, wproj, Wpt);

    gemm_bt<1><<<dim3(32, 24), 256, 0, stream>>>(Xb, Wqt, bqkv, (void*)Qb, Kb, Vt,
                                                 4096, 3072, 1024, qscale);
    attn_fwd16<<<dim3(16, 32), 512, 0, stream>>>(Qb, Kb, Vt, AO);
    gemm_bt<0><<<dim3(32, 8), 256, 0, stream>>>(AO, Wpt, bproj, (void*)out, nullptr, nullptr,
                                                4096, 1024, 1024, 1.0f);
}

// Round 21
// 110.945 us; speedup vs baseline: 1.1215x; 1.0221x over previous
//
#include <hip/hip_runtime.h>
#include <cstdint>

typedef __attribute__((ext_vector_type(8))) __bf16 bf16x8;
typedef __attribute__((ext_vector_type(4))) float f32x4;
typedef __attribute__((ext_vector_type(16))) float f32x16;
typedef __attribute__((ext_vector_type(4))) unsigned int u32x4;

#define DEV __device__ __forceinline__

DEV unsigned short f2bf(float f) {
    unsigned int u = __builtin_bit_cast(unsigned int, f);
    u += 0x7fffu + ((u >> 16) & 1u);   // RNE
    return (unsigned short)(u >> 16);
}

DEV void async_copy16(const void* g, void* l) {
    __builtin_amdgcn_global_load_lds(
        (const __attribute__((address_space(1))) unsigned int*)g,
        (__attribute__((address_space(3))) unsigned int*)l, 16, 0, 0);
}

DEV f32x4 mfma16(bf16x8 a, bf16x8 b, f32x4 c) {
    return __builtin_amdgcn_mfma_f32_16x16x32_bf16(a, b, c, 0, 0, 0);
}
DEV f32x16 mfma32(bf16x8 a, bf16x8 b, f32x16 c) {
    return __builtin_amdgcn_mfma_f32_32x32x16_bf16(a, b, c, 0, 0, 0);
}
DEV unsigned int cvtpk(float lo, float hi) {
    unsigned int d;
    asm("v_cvt_pk_bf16_f32 %0, %1, %2" : "=v"(d) : "v"(lo), "v"(hi));
    return d;
}
DEV float exp2f_fast(float x) { return __builtin_amdgcn_exp2f(x); }

// ---------------- fused preprocessing: X convert + both weight transposes ----------------
// blocks [0,4096): hs f32 -> Xb bf16 (1024 elems/block, vectorized)
// blocks [4096,8192): W[K][N] f32 -> Wt[N][K] bf16 (32x32 tiles; first 3072 wqkv, rest wproj)
__global__ __launch_bounds__(256) void prep(const float* __restrict__ hs,
                                            unsigned short* __restrict__ Xb,
                                            const float* __restrict__ W1,
                                            unsigned short* __restrict__ Wt1,
                                            const float* __restrict__ W2,
                                            unsigned short* __restrict__ Wt2) {
    const int flat = (int)blockIdx.x;
    if (flat < 4096) {
        const int i = (flat * 256 + (int)threadIdx.x) * 4;
        float4 v = *(const float4*)&hs[i];
        ushort4 o;
        o.x = f2bf(v.x); o.y = f2bf(v.y); o.z = f2bf(v.z); o.w = f2bf(v.w);
        *(ushort4*)&Xb[i] = o;
        return;
    }
    __shared__ float tile[32][33];
    const int f2 = flat - 4096;
    const float* W; unsigned short* Wt; int n0, k0, N;
    if (f2 < 3072) { W = W1; Wt = Wt1; N = 3072; n0 = (f2 % 96) * 32; k0 = (f2 / 96) * 32; }
    else           { W = W2; Wt = Wt2; N = 1024; n0 = ((f2 - 3072) % 32) * 32; k0 = ((f2 - 3072) / 32) * 32; }
    const int K = 1024;
    int tx = threadIdx.x & 31, ty = threadIdx.x >> 5;  // ty 0..7
#pragma unroll
    for (int i = 0; i < 32; i += 8)
        tile[ty + i][tx] = W[(size_t)(k0 + ty + i) * N + n0 + tx];
    __syncthreads();
#pragma unroll
    for (int i = 0; i < 32; i += 8)
        Wt[(size_t)(n0 + ty + i) * K + k0 + tx] = f2bf(tile[tx][ty + i]);
}

// ---------------- GEMM v5: triple-buffered BK=32, counted vmcnt ----------------
template <int QKVMODE>
__global__ __launch_bounds__(256) void gemm_bt(const unsigned short* __restrict__ A,
                                               const unsigned short* __restrict__ Bt,
                                               const float* __restrict__ bias,
                                               void* __restrict__ Cout,
                                               unsigned short* __restrict__ KbOut,
                                               unsigned short* __restrict__ VtOut,
                                               int M, int N, int K, float qscaleV) {
    __shared__ __align__(16) unsigned short Asl[3][128][32];
    __shared__ __align__(16) unsigned short Bsl[3][128][32];
    const int tid = threadIdx.x;
    const int lane = tid & 63, w = tid >> 6;
    const int cl = lane & 15, kg = lane >> 4;

    const int nwg = (int)(gridDim.x * gridDim.y);
    const int flat = (int)(blockIdx.y * gridDim.x + blockIdx.x);
    const int swzb = (flat & 7) * (nwg >> 3) + (flat >> 3);
    const int m0 = (swzb % (int)gridDim.x) * 128;
    const int n0 = (swzb / (int)gridDim.x) * 128;

    const int wm = (w >> 1) * 64, wn = (w & 1) * 64;

    f32x4 acc[4][4] = {};

    const int srow16 = lane >> 2;
    const int sc4 = (lane & 3) ^ ((lane >> 3) & 3);
    const int rdswz = (cl >> 1) & 3;

    const int T = K >> 5;
#define GSTAGE(buf, t)                                                                    \
    {                                                                                     \
        const int k0_ = (t) << 5;                                                         \
        _Pragma("unroll")                                                                 \
        for (int j = 0; j < 2; ++j) {                                                     \
            const int row = w * 32 + j * 16;                                              \
            async_copy16(A + (size_t)(m0 + row + srow16) * K + k0_ + sc4 * 8,             \
                         &Asl[buf][row][0]);                                              \
            async_copy16(Bt + (size_t)(n0 + row + srow16) * K + k0_ + sc4 * 8,            \
                         &Bsl[buf][row][0]);                                              \
        }                                                                                 \
    }

    GSTAGE(0, 0);
    if (T > 1) GSTAGE(1, 1);

    for (int t = 0; t < T; ++t) {
        if (t + 1 < T)
            asm volatile("s_waitcnt vmcnt(4) lgkmcnt(0)" ::: "memory");
        else
            asm volatile("s_waitcnt vmcnt(0) lgkmcnt(0)" ::: "memory");
        __syncthreads();
        if (t + 2 < T) GSTAGE((t + 2) % 3, t + 2);

        const int cur = t % 3;
        bf16x8 af[4], bfv[4];
#pragma unroll
        for (int mf = 0; mf < 4; ++mf)
            af[mf] = *(const bf16x8*)&Asl[cur][wm + mf * 16 + cl][(kg ^ rdswz) * 8];
#pragma unroll
        for (int nf = 0; nf < 4; ++nf)
            bfv[nf] = *(const bf16x8*)&Bsl[cur][wn + nf * 16 + cl][(kg ^ rdswz) * 8];
        __builtin_amdgcn_s_setprio(1);
#pragma unroll
        for (int mf = 0; mf < 4; ++mf)
#pragma unroll
            for (int nf = 0; nf < 4; ++nf)
                acc[mf][nf] = mfma16(af[mf], bfv[nf], acc[mf][nf]);
        __builtin_amdgcn_s_setprio(0);
    }
#undef GSTAGE

#pragma unroll
    for (int mf = 0; mf < 4; ++mf) {
#pragma unroll
        for (int nf = 0; nf < 4; ++nf) {
            const int col = n0 + wn + nf * 16 + cl;
            const float bv = bias[col];
            const int row0 = m0 + wm + mf * 16 + kg * 4;
            if (QKVMODE == 0) {
#pragma unroll
                for (int r = 0; r < 4; ++r)
                    ((float*)Cout)[(size_t)(row0 + r) * N + col] = acc[mf][nf][r] + bv;
            } else if (col < 1024) {            // Q plane (pre-scaled for exp2 softmax)
#pragma unroll
                for (int r = 0; r < 4; ++r)
                    ((unsigned short*)Cout)[(size_t)(row0 + r) * 1024 + col] =
                        f2bf((acc[mf][nf][r] + bv) * qscaleV);
            } else if (col < 2048) {            // K plane
#pragma unroll
                for (int r = 0; r < 4; ++r)
                    KbOut[(size_t)(row0 + r) * 1024 + (col - 1024)] = f2bf(acc[mf][nf][r] + bv);
            } else {                            // V -> transposed Vt plane
                const int pcol = col - 2048;    // h*64 + d
                const int hh = pcol >> 6, dd = pcol & 63;
                const int bb = row0 >> 11, ss = row0 & 2047;
                ushort4 o;
                o.x = f2bf(acc[mf][nf][0] + bv);
                o.y = f2bf(acc[mf][nf][1] + bv);
                o.z = f2bf(acc[mf][nf][2] + bv);
                o.w = f2bf(acc[mf][nf][3] + bv);
                *(ushort4*)&VtOut[((size_t)(bb * 16 + hh) * 64 + dd) * 2048 + ss] = o;
            }
        }
    }
}

// ---------------- flash attention v16: intra-block split-KV (8 waves) ----------------
// Measured-best attn (42.4-42.5 us). 8 waves = 4 row-groups x 2 KV-halves; fixed-offset
// softmax makes partials linear -> LDS merge, no atomics. XCD-local head mapping +
// complementary strip pairing (FETCH 12.3 MB).
__global__ __launch_bounds__(512) void attn_fwd16(const unsigned short* __restrict__ Qb,
                                                  const unsigned short* __restrict__ Kb,
                                                  const unsigned short* __restrict__ vt,
                                                  unsigned short* __restrict__ aout) {
    constexpr int S = 2048;
    constexpr float MOFF = 8.0f;                // fixed softmax offset (exp2 domain)
    __shared__ __align__(16) unsigned short SM[2][2][2][64 * 64];
    const int tid = threadIdx.x;
    const int l = tid & 63, w = tid >> 6;       // 8 waves
    const int q31 = l & 31, hi = l >> 5;
    const int rg = w & 3, kvh = w >> 2;         // row-group 0..3, kv-half 0..1

    // XCD-local mapping (R12) + complementary pairing
    const int id = (int)(blockIdx.y * gridDim.x + blockIdx.x);
    const int hblk = id >> 8, c = id & 255;
    const int x = c & 7, u = c >> 3;            // x = XCD, u = 0..31
    const int bh = x * 4 + (u & 3);
    const int j = u >> 2;                       // 0..7
    const int strip = hblk ? j : 15 - j;

    const int b = bh >> 4, h = bh & 15;
    const int q0 = strip * 128 + rg * 32;
    const int q = q0 + q31;
    const unsigned short* Qp = Qb + (size_t)b * S * 1024 + h * 64;
    const unsigned short* Kp = Kb + (size_t)b * S * 1024 + h * 64;
    const unsigned short* Vtp = vt + (size_t)bh * 64 * S;

    bf16x8 qf[4];
#pragma unroll
    for (int kf = 0; kf < 4; ++kf)
        qf[kf] = *(const bf16x8*)&Qp[(size_t)q * 1024 + kf * 16 + hi * 8];

    float lsum = 0.f;
    f32x16 oacc[2] = {};

    const int srow = l >> 3;                    // 0..7 within the 8-row group
    const int sc16 = (l & 7) ^ srow;            // pre-swizzled source col16
    const int swz = q31 & 7;                    // read-side XOR for this lane's rows

    const int Th = strip + 1;                   // tiles per KV-half
    const int row8 = w * 8;                     // this wave's 8-row slab

#define STAGE(buf, t)                                                                   \
    {                                                                                   \
        const int sA = (t) * 64;                                                        \
        const int sB = (Th + (t)) * 64;                                                 \
        async_copy16(Kp + (size_t)(sA + row8 + srow) * 1024 + sc16 * 8,                 \
                     &SM[0][buf][0][row8 * 64]);                                        \
        async_copy16(Kp + (size_t)(sB + row8 + srow) * 1024 + sc16 * 8,                 \
                     &SM[0][buf][1][row8 * 64]);                                        \
        async_copy16(Vtp + (size_t)(row8 + srow) * S + sA + sc16 * 8,                   \
                     &SM[1][buf][0][row8 * 64]);                                        \
        async_copy16(Vtp + (size_t)(row8 + srow) * S + sB + sc16 * 8,                   \
                     &SM[1][buf][1][row8 * 64]);                                        \
    }

    STAGE(0, 0);
    int cur = 0;

    for (int t = 0; t < Th; ++t) {
        // explicit drain (R7): staging writes landed, prev-buffer reads complete
        asm volatile("s_waitcnt vmcnt(0) lgkmcnt(0)" ::: "memory");
        __syncthreads();
        if (t + 1 < Th) STAGE(cur ^ 1, t + 1);

        const int s0 = (kvh * Th + t) * 64;

        // ---- K frags from swizzled LDS ----
        bf16x8 kb[2][4];
#pragma unroll
        for (int kt = 0; kt < 2; ++kt)
#pragma unroll
            for (int kf = 0; kf < 4; ++kf)
                kb[kt][kf] = *(const bf16x8*)&SM[0][cur][kvh][(kt * 32 + q31) * 64 + ((kf * 2 + hi) ^ swz) * 8];

        // ---- T[key][q] = K @ Q^T (swapped) ----
        f32x16 tacc[2] = {};
        __builtin_amdgcn_s_setprio(1);
#pragma unroll
        for (int kt = 0; kt < 2; ++kt)
#pragma unroll
            for (int kf = 0; kf < 4; ++kf)
                tacc[kt] = mfma32(kb[kt][kf], qf[kf], tacc[kt]);
        __builtin_amdgcn_s_setprio(0);

        // ---- V frags from swizzled LDS ----
        bf16x8 vb[2][4];
#pragma unroll
        for (int df = 0; df < 2; ++df)
#pragma unroll
            for (int ks = 0; ks < 4; ++ks)
                vb[df][ks] = *(const bf16x8*)&SM[1][cur][kvh][(df * 32 + q31) * 64 + ((ks * 2 + hi) ^ swz) * 8];

        // ---- causal mask: only partial tiles pay ----
        const bool partial = (s0 + 63 > q0);
        float pv[2][16];
        if (partial) {
#pragma unroll
            for (int kt = 0; kt < 2; ++kt)
#pragma unroll
                for (int r = 0; r < 16; ++r) {
                    const int key = s0 + kt * 32 + (r & 3) + ((r >> 2) << 3) + hi * 4;
                    float sv = tacc[kt][r];
                    if (key > q) sv = -1e30f;
                    pv[kt][r] = sv;
                }
        } else {
#pragma unroll
            for (int kt = 0; kt < 2; ++kt)
#pragma unroll
                for (int r = 0; r < 16; ++r) pv[kt][r] = tacc[kt][r];
        }

        // ---- exp2 (fixed offset) + pack + row sum ----
        unsigned int pk[2][4][2];
        float rsum = 0.f;
#pragma unroll
        for (int kt = 0; kt < 2; ++kt)
#pragma unroll
            for (int g = 0; g < 4; ++g) {
                const float e0 = exp2f_fast(pv[kt][g * 4 + 0] - MOFF);
                const float e1 = exp2f_fast(pv[kt][g * 4 + 1] - MOFF);
                const float e2 = exp2f_fast(pv[kt][g * 4 + 2] - MOFF);
                const float e3 = exp2f_fast(pv[kt][g * 4 + 3] - MOFF);
                pk[kt][g][0] = cvtpk(e0, e1);
                pk[kt][g][1] = cvtpk(e2, e3);
                rsum += (e0 + e1) + (e2 + e3);
            }
        rsum += __shfl_xor(rsum, 32, 64);
        lsum += rsum;

        // ---- PV: select-based PA assembly (shfl half-swap, verified) ----
#pragma unroll
        for (int ks = 0; ks < 4; ++ks) {
            const int kt = ks >> 1, kslo = ks & 1;
            const unsigned int pkA0 = pk[kt][2 * kslo][0],     pkA1 = pk[kt][2 * kslo][1];
            const unsigned int pkB0 = pk[kt][2 * kslo + 1][0], pkB1 = pk[kt][2 * kslo + 1][1];
            const unsigned int send0 = hi ? pkA0 : pkB0;
            const unsigned int send1 = hi ? pkA1 : pkB1;
            const unsigned int own0  = hi ? pkB0 : pkA0;
            const unsigned int own1  = hi ? pkB1 : pkA1;
            const unsigned int recv0 = (unsigned int)__shfl_xor((int)send0, 32, 64);
            const unsigned int recv1 = (unsigned int)__shfl_xor((int)send1, 32, 64);
            u32x4 u4;
            u4[0] = hi ? recv0 : own0;
            u4[1] = hi ? recv1 : own1;
            u4[2] = hi ? own0 : recv0;
            u4[3] = hi ? own1 : recv1;
            const bf16x8 pa = __builtin_bit_cast(bf16x8, u4);
            __builtin_amdgcn_s_setprio(1);
            oacc[0] = mfma32(pa, vb[0][ks], oacc[0]);
            oacc[1] = mfma32(pa, vb[1][ks], oacc[1]);
            __builtin_amdgcn_s_setprio(0);
        }
        cur ^= 1;
    }
#undef STAGE

    // ---- merge halves (LINEAR: fixed-offset softmax has no running max) ----
    asm volatile("s_waitcnt vmcnt(0) lgkmcnt(0)" ::: "memory");
    __syncthreads();                            // loop LDS reads done; safe to reuse
    float* fl = (float*)&SM[0][0][0][0];        // [4][64][36] f32 = 36 KB
    float* p = fl + ((size_t)rg * 64 + l) * 36; // 144 B stride (16B-aligned)
    if (kvh == 1) {
#pragma unroll
        for (int d = 0; d < 2; ++d)
#pragma unroll
            for (int g = 0; g < 4; ++g)
                *(f32x4*)(p + d * 16 + g * 4) = f32x4{oacc[d][g * 4 + 0], oacc[d][g * 4 + 1],
                                                      oacc[d][g * 4 + 2], oacc[d][g * 4 + 3]};
        p[32] = lsum;
    }
    asm volatile("s_waitcnt lgkmcnt(0)" ::: "memory");
    __syncthreads();
    if (kvh == 1) return;

#pragma unroll
    for (int d = 0; d < 2; ++d)
#pragma unroll
        for (int g = 0; g < 4; ++g) {
            const f32x4 v = *(const f32x4*)(p + d * 16 + g * 4);
#pragma unroll
            for (int e = 0; e < 4; ++e) oacc[d][g * 4 + e] += v[e];
        }
    lsum += p[32];

    // ---- epilogue: O /= l ----
    const float linv = 1.f / lsum;
#pragma unroll
    for (int r = 0; r < 16; ++r) {
        const int qrow = (r & 3) + ((r >> 2) << 3) + hi * 4;
        const float lr = __shfl(linv, qrow, 64);
        const int row = q0 + qrow;
        aout[(size_t)(b * S + row) * 1024 + h * 64 + q31]      = f2bf(oacc[0][r] * lr);
        aout[(size_t)(b * S + row) * 1024 + h * 64 + 32 + q31] = f2bf(oacc[1][r] * lr);
    }
}

extern "C" void kernel_launch(void* const* d_in, const int* in_sizes, int n_in,
                              void* d_out, int out_size, void* d_ws, size_t ws_size,
                              hipStream_t stream) {
    (void)in_sizes; (void)n_in; (void)out_size; (void)ws_size;
    const float* hs    = (const float*)d_in[0];  // [2,2048,1024]
    const float* wqkv  = (const float*)d_in[1];  // [1024,3072]
    const float* bqkv  = (const float*)d_in[2];  // [3072]
    const float* wproj = (const float*)d_in[3];  // [1024,1024]
    const float* bproj = (const float*)d_in[4];  // [1024]
    float* out = (float*)d_out;                  // [2,2048,1024] f32

    unsigned short* Xb  = (unsigned short*)d_ws;                 // 4096*1024
    unsigned short* Wqt = Xb  + (size_t)4096 * 1024;             // 3072*1024
    unsigned short* Wpt = Wqt + (size_t)3072 * 1024;             // 1024*1024
    unsigned short* Qb  = Wpt + (size_t)1024 * 1024;             // 4096*1024
    unsigned short* Kb  = Qb  + (size_t)4096 * 1024;             // 4096*1024
    unsigned short* Vt  = Kb  + (size_t)4096 * 1024;             // 32*64*2048
    unsigned short* AO  = Vt  + (size_t)4096 * 1024;             // 4096*1024

    const float qscale = 0.125f * 1.4426950408889634f;  // softmax scale + log2e into Q

    prep<<<8192, 256, 0, stream>>>(hs, Xb, wqkv, Wqt, wproj, Wpt);

    gemm_bt<1><<<dim3(32, 24), 256, 0, stream>>>(Xb, Wqt, bqkv, (void*)Qb, Kb, Vt,
                                                 4096, 3072, 1024, qscale);
    attn_fwd16<<<dim3(16, 32), 512, 0, stream>>>(Qb, Kb, Vt, AO);
    gemm_bt<0><<<dim3(32, 8), 256, 0, stream>>>(AO, Wpt, bproj, (void*)out, nullptr, nullptr,
                                                4096, 1024, 1024, 1.0f);
}